// Round 1
// 380.059 us; speedup vs baseline: 1.0023x; 1.0023x over previous
//
#include <hip/hip_runtime.h>

// KL(N(mu_p, diag(exp(ls_p))) || N(mu_q, diag(exp(ls_q)))), closed form,
// reduced to a single scalar:
//   out = 0.5 * ( S / N_samples - d )
// where S = sum over ALL elements of
//   elem = (ls_q - ls_p) + exp(ls_p - ls_q) + (m_q - m_p)^2 * exp(-ls_q)
// Shapes: (2, 3, 160, 192, 160) fp32. N_total = 29,491,200 (divisible by 4).
// N_samples = N_total / d = 9,830,400, d = 3.
//
// Memory-bound: 4 arrays * 118 MB = 472 MB read -> ~75 us at 6.3 TB/s.
// Previous version: VGPR_Count=16 -> compiler serialized loads (vmcnt(0)
// between iterations), only ~2-4 loads in flight per wave -> latency-bound
// at 3.4 TB/s effective. This version: UNROLL=4 explicit register batches
// (16 x float4 = 256 B outstanding per thread) to restore memory-level
// parallelism. fp64 per-thread accumulate, wave shuffle reduce, LDS across
// waves, one double partial per block, single-block finalize kernel.

#define BLOCKS   2048
#define THREADS  256
#define UNROLL   4

__global__ __launch_bounds__(THREADS) void kl_reduce_kernel(
    const float4* __restrict__ mp, const float4* __restrict__ lsp,
    const float4* __restrict__ mq, const float4* __restrict__ lsq,
    double* __restrict__ partials, long n4)
{
    const long chunk   = (long)THREADS * UNROLL;   // 1024 float4 per chunk
    const long nchunks = n4 / chunk;               // 7200 for this shape
    const int  t       = threadIdx.x;

    double acc = 0.0;

    // Main loop: grid-stride over contiguous chunks. Each thread issues all
    // 16 loads (coalesced: lane t reads float4 t + u*THREADS) before any
    // compute, so the compiler keeps them in flight together.
    for (long c = blockIdx.x; c < nchunks; c += gridDim.x) {
        const long base = c * chunk + t;

        float4 A[UNROLL], B[UNROLL], C[UNROLL], D[UNROLL];
#pragma unroll
        for (int u = 0; u < UNROLL; ++u) A[u] = mp [base + (long)u * THREADS];
#pragma unroll
        for (int u = 0; u < UNROLL; ++u) B[u] = lsp[base + (long)u * THREADS];
#pragma unroll
        for (int u = 0; u < UNROLL; ++u) C[u] = mq [base + (long)u * THREADS];
#pragma unroll
        for (int u = 0; u < UNROLL; ++u) D[u] = lsq[base + (long)u * THREADS];

#pragma unroll
        for (int u = 0; u < UNROLL; ++u) {
            float dx = C[u].x - A[u].x;
            float dy = C[u].y - A[u].y;
            float dz = C[u].z - A[u].z;
            float dw = C[u].w - A[u].w;

            // r = ls_q - ls_p; elem = r + exp(-r) + diff^2 * exp(-ls_q)
            float rx = D[u].x - B[u].x;
            float ry = D[u].y - B[u].y;
            float rz = D[u].z - B[u].z;
            float rw = D[u].w - B[u].w;

            float eqx = __expf(-D[u].x);
            float eqy = __expf(-D[u].y);
            float eqz = __expf(-D[u].z);
            float eqw = __expf(-D[u].w);

            float e0 = rx + __expf(-rx) + dx * dx * eqx;
            float e1 = ry + __expf(-ry) + dy * dy * eqy;
            float e2 = rz + __expf(-rz) + dz * dz * eqz;
            float e3 = rw + __expf(-rw) + dw * dw * eqw;

            acc += (double)((e0 + e1) + (e2 + e3));
        }
    }

    // Tail: any float4s beyond the last full chunk (none for this shape,
    // but keep it correct for general n4).
    for (long i = nchunks * chunk + (long)blockIdx.x * blockDim.x + t;
         i < n4; i += (long)gridDim.x * blockDim.x) {
        float4 a = mp[i], b = lsp[i], c = mq[i], d = lsq[i];
        float dx = c.x - a.x, dy = c.y - a.y, dz = c.z - a.z, dw = c.w - a.w;
        float rx = d.x - b.x, ry = d.y - b.y, rz = d.z - b.z, rw = d.w - b.w;
        float e0 = rx + __expf(-rx) + dx * dx * __expf(-d.x);
        float e1 = ry + __expf(-ry) + dy * dy * __expf(-d.y);
        float e2 = rz + __expf(-rz) + dz * dz * __expf(-d.z);
        float e3 = rw + __expf(-rw) + dw * dw * __expf(-d.w);
        acc += (double)((e0 + e1) + (e2 + e3));
    }

    // wave (64-lane) reduction
#pragma unroll
    for (int off = 32; off > 0; off >>= 1)
        acc += __shfl_down(acc, off, 64);

    __shared__ double sdata[THREADS / 64];
    int wave = threadIdx.x >> 6;
    if ((threadIdx.x & 63) == 0) sdata[wave] = acc;
    __syncthreads();

    if (threadIdx.x == 0) {
        double s = 0.0;
#pragma unroll
        for (int w = 0; w < THREADS / 64; ++w) s += sdata[w];
        partials[blockIdx.x] = s;
    }
}

__global__ __launch_bounds__(256) void kl_finalize_kernel(
    const double* __restrict__ partials, int nblocks,
    float* __restrict__ out, double inv_nsamp, double dch)
{
    double acc = 0.0;
    for (int i = threadIdx.x; i < nblocks; i += blockDim.x)
        acc += partials[i];

#pragma unroll
    for (int off = 32; off > 0; off >>= 1)
        acc += __shfl_down(acc, off, 64);

    __shared__ double sdata[4];
    int wave = threadIdx.x >> 6;
    if ((threadIdx.x & 63) == 0) sdata[wave] = acc;
    __syncthreads();

    if (threadIdx.x == 0) {
        double s = 0.0;
#pragma unroll
        for (int w = 0; w < 4; ++w) s += sdata[w];
        out[0] = (float)(0.5 * (s * inv_nsamp - dch));
    }
}

extern "C" void kernel_launch(void* const* d_in, const int* in_sizes, int n_in,
                              void* d_out, int out_size, void* d_ws, size_t ws_size,
                              hipStream_t stream) {
    const float4* mp  = (const float4*)d_in[0];
    const float4* lsp = (const float4*)d_in[1];
    const float4* mq  = (const float4*)d_in[2];
    const float4* lsq = (const float4*)d_in[3];

    long n_total = (long)in_sizes[0];       // 29,491,200
    long n4 = n_total / 4;                  // exactly divisible
    const long d_ch = 3;
    double n_samples = (double)(n_total / d_ch);

    double* partials = (double*)d_ws;       // BLOCKS * 8 bytes = 16 KB

    kl_reduce_kernel<<<BLOCKS, THREADS, 0, stream>>>(mp, lsp, mq, lsq, partials, n4);
    kl_finalize_kernel<<<1, 256, 0, stream>>>(partials, BLOCKS, (float*)d_out,
                                              1.0 / n_samples, (double)d_ch);
}